// Round 1
// baseline (347.918 us; speedup 1.0000x reference)
//
#include <hip/hip_runtime.h>

#define BB   4
#define NN   256
#define TT   4096
#define DD   128      // SIM_DIM
#define LK   101      // LOOKUP
#define PADK 50
#define OD   128      // OUT_DIM
#define ROWS 164      // 64 + LK - 1 rows of halo'd proj window
#define RSTR 33       // row stride in float4 units (132 floats, +4 pad for bank spread)

// ---------------- kernel 1: one-time weight transposes ----------------
__global__ __launch_bounds__(256) void transpose_w_kernel(
    const float* __restrict__ w_proj, const float* __restrict__ w_fc,
    float* __restrict__ w_t, float* __restrict__ wfc_t) {
  int idx = blockIdx.x * 256 + threadIdx.x;
  int stride = gridDim.x * 256;
  // w_proj [128 d][256 n] -> w_t [256 n][128 d]
  for (int i = idx; i < DD * NN; i += stride) {
    int d = i / NN, n = i - d * NN;        // read coalesced over n
    w_t[n * DD + d] = w_proj[i];
  }
  // w_fc [128 o][101 j] -> wfc_t [101 j][128 o]
  for (int i = idx; i < OD * LK; i += stride) {
    int o = i / LK, j = i - o * LK;
    wfc_t[j * OD + o] = w_fc[i];
  }
}

// ---------------- kernel 2: spatial mean-pool (HBM-bound, coalesced) ----------------
// Each block: 64 rows x 48 floats = 3072 floats, fully coalesced float4 loads.
__global__ __launch_bounds__(256) void pool_kernel(
    const float* __restrict__ x, float* __restrict__ feat) {
  __shared__ float part[768];
  size_t base = (size_t)blockIdx.x * 3072;
  const float4* x4 = (const float4*)(x + base);
  int tid = threadIdx.x;
#pragma unroll
  for (int p = 0; p < 3; ++p) {
    float4 v = x4[p * 256 + tid];
    part[p * 256 + tid] = v.x + v.y + v.z + v.w;
  }
  __syncthreads();
  if (tid < 64) {
    float s = 0.f;
#pragma unroll
    for (int i = 0; i < 12; ++i) s += part[tid * 12 + i];
    feat[(size_t)blockIdx.x * 64 + tid] = s * (1.0f / 48.0f);
  }
}

// ---------------- kernel 3: projection + L2 normalize ----------------
// grid = B * T/64 blocks; wave w handles d in [32w,32w+32), lane = tt.
__global__ __launch_bounds__(256, 1) void proj_kernel(
    const float* __restrict__ feat, const float* __restrict__ w_t,
    float* __restrict__ projn) {
  extern __shared__ float smemB[];
  float* fs = smemB;            // [256 n][64 tt]
  float* ss = smemB + NN * 64;  // [4 w][64 tt]
  int b = blockIdx.x >> 6;
  int t0 = (blockIdx.x & 63) << 6;
  int tid = threadIdx.x;

  const float* fb = feat + ((size_t)b * NN) * TT + t0;
  for (int i = tid; i < NN * 64; i += 256) {
    int n = i >> 6, u = i & 63;
    fs[i] = fb[(size_t)n * TT + u];   // coalesced per row
  }
  __syncthreads();

  int w = tid >> 6, lane = tid & 63;
  int d0 = w * 32;
  float acc[32];
#pragma unroll
  for (int k = 0; k < 32; ++k) acc[k] = 0.f;

  for (int n = 0; n < NN; ++n) {
    float f = fs[n * 64 + lane];                     // conflict-free (stride 1)
    const float4* wr = (const float4*)(w_t + n * DD + d0);  // wave-uniform, L1/L2
#pragma unroll
    for (int k = 0; k < 8; ++k) {
      float4 wv = wr[k];
      acc[4 * k + 0] += wv.x * f;
      acc[4 * k + 1] += wv.y * f;
      acc[4 * k + 2] += wv.z * f;
      acc[4 * k + 3] += wv.w * f;
    }
  }

  float s2 = 0.f;
#pragma unroll
  for (int k = 0; k < 32; ++k) s2 += acc[k] * acc[k];
  ss[w * 64 + lane] = s2;
  __syncthreads();
  float tot = ss[lane] + ss[64 + lane] + ss[128 + lane] + ss[192 + lane];
  float inv = 1.0f / fmaxf(sqrtf(tot), 1e-12f);

  float4* po = (float4*)(projn + ((size_t)(b * TT + t0 + lane)) * DD + d0);
#pragma unroll
  for (int k = 0; k < 8; ++k) {
    float4 o;
    o.x = acc[4 * k + 0] * inv;
    o.y = acc[4 * k + 1] * inv;
    o.z = acc[4 * k + 2] * inv;
    o.w = acc[4 * k + 3] * inv;
    po[k] = o;
  }
}

// ---------------- kernel 4: banded cosine sims + FC + ReLU ----------------
// grid = B * T/64 = 256 blocks (one per CU). Lane = tt (own row in 128 VGPRs),
// s = tt + j scanned wave-parallel so "other" row is a wave-uniform LDS broadcast.
__global__ __launch_bounds__(256, 1) void band_fc_kernel(
    const float* __restrict__ projn, const float* __restrict__ wfc_t,
    const float* __restrict__ b_fc, float* __restrict__ out) {
  extern __shared__ float4 smemC[];
  float4* p4 = smemC;                            // [ROWS][RSTR] float4
  float* band = (float*)(smemC + ROWS * RSTR);   // [64][LK]
  int b = blockIdx.x >> 6;
  int t0 = (blockIdx.x & 63) << 6;
  int tid = threadIdx.x;

  // stage proj rows [t0-50, t0+113], zero-filled OOB (matches zero padding)
  const float4* pg = (const float4*)projn;
  for (int i = tid; i < ROWS * 32; i += 256) {
    int r = i >> 5, c = i & 31;
    int t = t0 + r - PADK;
    float4 v = make_float4(0.f, 0.f, 0.f, 0.f);
    if (t >= 0 && t < TT) v = pg[(((size_t)b * TT + t) << 5) + c];
    p4[r * RSTR + c] = v;
  }
  __syncthreads();

  int w = tid >> 6, tt = tid & 63;

  // phase 1: band[tt][j] = dot(p[tt+50], p[tt+j]); own row in registers
  float4 own[32];
#pragma unroll
  for (int c = 0; c < 32; ++c) own[c] = p4[(tt + PADK) * RSTR + c];

  int s0 = w * 41;
  int sEnd = (w == 3) ? ROWS : (s0 + 41);
  for (int s = s0; s < sEnd; ++s) {
    float a = 0.f;
#pragma unroll
    for (int c = 0; c < 32; ++c) {
      float4 ov = p4[s * RSTR + c];   // wave-uniform -> LDS broadcast
      a += own[c].x * ov.x + own[c].y * ov.y + own[c].z * ov.z + own[c].w * ov.w;
    }
    int j = s - tt;
    if (j >= 0 && j < LK) band[tt * LK + j] = a;
  }
  __syncthreads();

  // phase 2: out[tt][o] = relu(b_fc[o] + sum_j band[tt][j] * w_fc[o][j])
  int o0 = w * 32;
  float acc[32];
  const float4* bf4 = (const float4*)(b_fc + o0);
#pragma unroll
  for (int k = 0; k < 8; ++k) {
    float4 bv = bf4[k];
    acc[4 * k + 0] = bv.x; acc[4 * k + 1] = bv.y;
    acc[4 * k + 2] = bv.z; acc[4 * k + 3] = bv.w;
  }
  for (int j = 0; j < LK; ++j) {
    float bv = band[tt * LK + j];     // stride 101: gcd(101,32)=1, conflict-free
    const float4* wr = (const float4*)(wfc_t + j * OD + o0);  // wave-uniform
#pragma unroll
    for (int k = 0; k < 8; ++k) {
      float4 wv = wr[k];
      acc[4 * k + 0] += wv.x * bv;
      acc[4 * k + 1] += wv.y * bv;
      acc[4 * k + 2] += wv.z * bv;
      acc[4 * k + 3] += wv.w * bv;
    }
  }
  float4* og = (float4*)(out + ((size_t)(b * TT + t0 + tt)) * OD + o0);
#pragma unroll
  for (int k = 0; k < 8; ++k) {
    float4 o;
    o.x = fmaxf(acc[4 * k + 0], 0.f);
    o.y = fmaxf(acc[4 * k + 1], 0.f);
    o.z = fmaxf(acc[4 * k + 2], 0.f);
    o.w = fmaxf(acc[4 * k + 3], 0.f);
    og[k] = o;
  }
}

extern "C" void kernel_launch(void* const* d_in, const int* in_sizes, int n_in,
                              void* d_out, int out_size, void* d_ws, size_t ws_size,
                              hipStream_t stream) {
  const float* x      = (const float*)d_in[0];
  const float* w_proj = (const float*)d_in[1];
  const float* w_fc   = (const float*)d_in[2];
  const float* b_fc   = (const float*)d_in[3];
  float* out = (float*)d_out;

  // workspace layout (25.3 MB total)
  char* ws = (char*)d_ws;
  float* feat  = (float*)ws;                                    // B*N*T f32  = 16,777,216 B
  float* projn = (float*)(ws + 16777216);                       // B*T*D f32  =  8,388,608 B
  float* w_t   = (float*)(ws + 16777216 + 8388608);             // N*D f32    =    131,072 B
  float* wfc_t = (float*)(ws + 16777216 + 8388608 + 131072);    // LK*OD f32  =     51,712 B

  size_t smB = (size_t)(NN * 64 + 4 * 64) * sizeof(float);              // 66,560 B
  size_t smC = (size_t)ROWS * RSTR * sizeof(float4) + (size_t)64 * LK * sizeof(float); // 112,448 B
  hipFuncSetAttribute((const void*)proj_kernel,
                      hipFuncAttributeMaxDynamicSharedMemorySize, (int)smB);
  hipFuncSetAttribute((const void*)band_fc_kernel,
                      hipFuncAttributeMaxDynamicSharedMemorySize, (int)smC);

  transpose_w_kernel<<<64, 256, 0, stream>>>(w_proj, w_fc, w_t, wfc_t);
  pool_kernel<<<(BB * NN * TT) / 64, 256, 0, stream>>>(x, feat);
  proj_kernel<<<BB * (TT / 64), 256, smB, stream>>>(feat, w_t, projn);
  band_fc_kernel<<<BB * (TT / 64), 256, smC, stream>>>(projn, wfc_t, b_fc, out);
}

// Round 3
// 224.179 us; speedup vs baseline: 1.5520x; 1.5520x over previous
//
#include <hip/hip_runtime.h>

#define BB   4
#define NN   256
#define TT   4096
#define DD   128      // SIM_DIM
#define LK   101      // LOOKUP
#define PADK 50
#define OD   128      // OUT_DIM
#define ROWS 164      // 64 + LK - 1 rows of halo'd proj window
#define RSTR 33       // row stride in float4 units (132 floats, +4 pad)
#define FSTR 260      // feat LDS row stride in floats ([t][n] layout, +4 pad)
#define CPB  8        // pool chunks per block

typedef float vfloat4 __attribute__((ext_vector_type(4)));  // native vector for nontemporal builtin

// ---------------- kernel 1: one-time weight transposes ----------------
__global__ __launch_bounds__(256) void transpose_w_kernel(
    const float* __restrict__ w_proj, const float* __restrict__ w_fc,
    float* __restrict__ w_t, float* __restrict__ wfc_t) {
  int idx = blockIdx.x * 256 + threadIdx.x;
  int stride = gridDim.x * 256;
  for (int i = idx; i < DD * NN; i += stride) {
    int d = i / NN, n = i - d * NN;
    w_t[n * DD + d] = w_proj[i];
  }
  for (int i = idx; i < OD * LK; i += stride) {
    int o = i / LK, j = i - o * LK;
    wfc_t[j * OD + o] = w_fc[i];
  }
}

// ---------------- kernel 2: spatial mean-pool (HBM-bound) ----------------
// 8192 blocks x 8 chunks; chunk = 64 t x 48 floats, fully coalesced.
__global__ __launch_bounds__(256) void pool_kernel(
    const float* __restrict__ x, float* __restrict__ feat) {
  __shared__ float part[2][768];
  int tid = threadIdx.x;
  for (int c = 0; c < CPB; ++c) {
    size_t ck = (size_t)blockIdx.x * CPB + c;
    const vfloat4* x4 = (const vfloat4*)(x + ck * 3072);
    float* pb = part[c & 1];
#pragma unroll
    for (int p = 0; p < 3; ++p) {
      vfloat4 v = __builtin_nontemporal_load(&x4[p * 256 + tid]);
      pb[p * 256 + tid] = v.x + v.y + v.z + v.w;
    }
    __syncthreads();
    if (tid < 64) {
      float s = 0.f;
#pragma unroll
      for (int i = 0; i < 12; ++i) s += pb[tid * 12 + i];
      feat[ck * 64 + tid] = s * (1.0f / 48.0f);
    }
  }
}

// ---------------- kernel 3: projection + L2 normalize ----------------
// 512 threads = 8 waves; wave w: d-slice [16w,16w+16); lane = tt.
// feat staged transposed [t][260] so lanes read 4 n's per ds_read_b128.
__global__ __launch_bounds__(512, 1) void proj_kernel(
    const float* __restrict__ feat, const float* __restrict__ w_t,
    float* __restrict__ projn) {
  extern __shared__ float smemB[];
  float* fs = smemB;              // [64 t][260]
  float* ss = smemB + 64 * FSTR;  // [8 w][64 t]
  int b = blockIdx.x >> 6;
  int t0 = (blockIdx.x & 63) << 6;
  int tid = threadIdx.x;

  const float* fb = feat + ((size_t)b * NN) * TT + t0;
  for (int i = tid; i < NN * 64; i += 512) {
    int n = i >> 6, u = i & 63;
    fs[u * FSTR + n] = fb[(size_t)n * TT + u];  // coalesced read, transposed store
  }
  __syncthreads();

  int w = tid >> 6, lane = tid & 63;
  int d0u = __builtin_amdgcn_readfirstlane((tid >> 6) * 16);
  float acc[16];
#pragma unroll
  for (int k = 0; k < 16; ++k) acc[k] = 0.f;

  const float* fsr = fs + lane * FSTR;
  for (int n = 0; n < NN; n += 4) {
    float4 f = *(const float4*)(fsr + n);          // 1 ds_read_b128 = 4 n's
    const float* wrow = w_t + n * DD + d0u;        // uniform address
#pragma unroll
    for (int q = 0; q < 4; ++q) {
      float fq = (q == 0) ? f.x : (q == 1) ? f.y : (q == 2) ? f.z : f.w;
      const float4* wv4 = (const float4*)(wrow + q * DD);
#pragma unroll
      for (int k = 0; k < 4; ++k) {
        float4 wv = wv4[k];
        acc[4 * k + 0] += wv.x * fq;
        acc[4 * k + 1] += wv.y * fq;
        acc[4 * k + 2] += wv.z * fq;
        acc[4 * k + 3] += wv.w * fq;
      }
    }
  }

  float s2 = 0.f;
#pragma unroll
  for (int k = 0; k < 16; ++k) s2 += acc[k] * acc[k];
  ss[w * 64 + lane] = s2;
  __syncthreads();
  float tot = 0.f;
#pragma unroll
  for (int q = 0; q < 8; ++q) tot += ss[q * 64 + lane];
  float inv = 1.0f / fmaxf(sqrtf(tot), 1e-12f);

  float4* po = (float4*)(projn + ((size_t)(b * TT + t0 + lane)) * DD + d0u);
#pragma unroll
  for (int k = 0; k < 4; ++k) {
    float4 o;
    o.x = acc[4 * k + 0] * inv;
    o.y = acc[4 * k + 1] * inv;
    o.z = acc[4 * k + 2] * inv;
    o.w = acc[4 * k + 3] * inv;
    po[k] = o;
  }
}

// ---------------- kernel 4: banded cosine sims + FC + ReLU ----------------
// 512 threads = 8 waves. Phase 1: own row (lane tt) in 128 VGPRs, scan s
// (21/wave), other row = wave-uniform LDS broadcast. Phase 2: o-slice 16/wave.
__global__ __launch_bounds__(512, 1) void band_fc_kernel(
    const float* __restrict__ projn, const float* __restrict__ wfc_t,
    const float* __restrict__ b_fc, float* __restrict__ out) {
  extern __shared__ float4 smemC[];
  float4* p4 = smemC;                            // [ROWS][RSTR]
  float* band = (float*)(smemC + ROWS * RSTR);   // [64][101]
  int b = blockIdx.x >> 6;
  int t0 = (blockIdx.x & 63) << 6;
  int tid = threadIdx.x;

  const float4* pg = (const float4*)projn;
  for (int i = tid; i < ROWS * 32; i += 512) {
    int r = i >> 5, c = i & 31;
    int t = t0 + r - PADK;
    float4 v = make_float4(0.f, 0.f, 0.f, 0.f);
    if (t >= 0 && t < TT) v = pg[(((size_t)b * TT + t) << 5) + c];
    p4[r * RSTR + c] = v;
  }
  __syncthreads();

  int w = tid >> 6, tt = tid & 63;

  float4 own[32];
#pragma unroll
  for (int c = 0; c < 32; ++c) own[c] = p4[(tt + PADK) * RSTR + c];

  int s0 = w * 21;
  int sEnd = (s0 + 21 < ROWS) ? (s0 + 21) : ROWS;
  for (int s = s0; s < sEnd; ++s) {
    float a = 0.f;
#pragma unroll
    for (int c = 0; c < 32; ++c) {
      float4 ov = p4[s * RSTR + c];   // wave-uniform -> LDS broadcast
      a += own[c].x * ov.x + own[c].y * ov.y + own[c].z * ov.z + own[c].w * ov.w;
    }
    int j = s - tt;
    if (j >= 0 && j < LK) band[tt * LK + j] = a;
  }
  __syncthreads();

  int o0u = __builtin_amdgcn_readfirstlane((tid >> 6) * 16);
  float acc[16];
  const float4* bf4 = (const float4*)(b_fc + o0u);
#pragma unroll
  for (int k = 0; k < 4; ++k) {
    float4 bv = bf4[k];
    acc[4 * k + 0] = bv.x; acc[4 * k + 1] = bv.y;
    acc[4 * k + 2] = bv.z; acc[4 * k + 3] = bv.w;
  }
#pragma unroll 2
  for (int j = 0; j < LK; ++j) {
    float bv = band[tt * LK + j];                 // gcd(101,32)=1: conflict-free
    const float4* wr = (const float4*)(wfc_t + j * OD + o0u);  // uniform
#pragma unroll
    for (int k = 0; k < 4; ++k) {
      float4 wv = wr[k];
      acc[4 * k + 0] += wv.x * bv;
      acc[4 * k + 1] += wv.y * bv;
      acc[4 * k + 2] += wv.z * bv;
      acc[4 * k + 3] += wv.w * bv;
    }
  }
  float4* og = (float4*)(out + ((size_t)(b * TT + t0 + tt)) * OD + o0u);
#pragma unroll
  for (int k = 0; k < 4; ++k) {
    float4 o;
    o.x = fmaxf(acc[4 * k + 0], 0.f);
    o.y = fmaxf(acc[4 * k + 1], 0.f);
    o.z = fmaxf(acc[4 * k + 2], 0.f);
    o.w = fmaxf(acc[4 * k + 3], 0.f);
    og[k] = o;
  }
}

extern "C" void kernel_launch(void* const* d_in, const int* in_sizes, int n_in,
                              void* d_out, int out_size, void* d_ws, size_t ws_size,
                              hipStream_t stream) {
  const float* x      = (const float*)d_in[0];
  const float* w_proj = (const float*)d_in[1];
  const float* w_fc   = (const float*)d_in[2];
  const float* b_fc   = (const float*)d_in[3];
  float* out = (float*)d_out;

  char* ws = (char*)d_ws;
  float* feat  = (float*)ws;                                    // B*N*T f32
  float* projn = (float*)(ws + 16777216);                       // B*T*D f32
  float* w_t   = (float*)(ws + 16777216 + 8388608);             // N*D f32
  float* wfc_t = (float*)(ws + 16777216 + 8388608 + 131072);    // LK*OD f32

  size_t smB = (size_t)(64 * FSTR + 8 * 64) * sizeof(float);                           // 68,608 B
  size_t smC = (size_t)ROWS * RSTR * sizeof(float4) + (size_t)64 * LK * sizeof(float); // 112,448 B
  (void)hipFuncSetAttribute((const void*)proj_kernel,
                      hipFuncAttributeMaxDynamicSharedMemorySize, (int)smB);
  (void)hipFuncSetAttribute((const void*)band_fc_kernel,
                      hipFuncAttributeMaxDynamicSharedMemorySize, (int)smC);

  transpose_w_kernel<<<64, 256, 0, stream>>>(w_proj, w_fc, w_t, wfc_t);
  pool_kernel<<<(BB * NN * TT) / (64 * CPB), 256, 0, stream>>>(x, feat);
  proj_kernel<<<BB * (TT / 64), 512, smB, stream>>>(feat, w_t, projn);
  band_fc_kernel<<<BB * (TT / 64), 512, smC, stream>>>(projn, wfc_t, b_fc, out);
}